// Round 1
// 439.867 us; speedup vs baseline: 1.0173x; 1.0173x over previous
//
#include <hip/hip_runtime.h>
#include <math.h>

// Problem constants (match reference)
#define DIM_EMB 1024
#define TIMESTEP 4096
#define BATCH 16

// out[b,t,c] = x[b,t,c] * sqrt(D) + pe[t,c]
// pe[t,c] = sin(t * 10000^(-2c/D)) for even c, cos(...) for odd c.
//
// Pure streaming: 256 MiB read + 256 MiB write, PE lives in registers.
// One block per t-row; each thread owns one float4 column slot and the
// 16 batch planes that share its PE values.
//
// v2 (this round): maximize memory-level parallelism. Issue ALL 16 batch
// loads before any store (16 outstanding global_load_dwordx4 per lane,
// 64 data VGPRs), then fma+store. Both streams use nontemporal (nt)
// hints — one-touch data, L2/LLC allocation is pure pollution (the
// harness poison-fills evict everything between iterations anyway).

typedef float f4 __attribute__((ext_vector_type(4)));

__global__ __launch_bounds__(256)
void Pos_embedding_39161511805397_kernel(const float* __restrict__ x,
                                         float* __restrict__ out) {
    const int t   = blockIdx.x;       // 0..TIMESTEP-1
    const int tid = threadIdx.x;      // 0..255
    const int c0  = tid << 2;         // column of .x component (even)

    const float pos = (float)t;
    // inv(c) = 10000^(-2c/D) = exp2( -log2(10000) / (D/2) * c )
    const float k = -13.287712379549449f / 512.0f;  // -log2(10000) / (D/2)
    const float a0 = pos * exp2f(k * (float)(c0 + 0));
    const float a1 = pos * exp2f(k * (float)(c0 + 1));
    const float a2 = pos * exp2f(k * (float)(c0 + 2));
    const float a3 = pos * exp2f(k * (float)(c0 + 3));

    f4 pe;
    pe.x = sinf(a0);   // even col
    pe.y = cosf(a1);   // odd col
    pe.z = sinf(a2);   // even col
    pe.w = cosf(a3);   // odd col

    const float s = 32.0f;  // sqrt(1024), exact

    const f4* __restrict__ xv = (const f4*)x;
    f4* __restrict__ ov       = (f4*)out;

    const size_t base   = ((size_t)t * DIM_EMB + (size_t)c0) >> 2;  // float4 units
    const size_t stride = ((size_t)TIMESTEP * DIM_EMB) >> 2;        // per batch

    // Phase 1: issue all 16 loads (deep MLP; fully unrolled => static
    // indices, array stays in VGPRs — no scratch).
    f4 v[BATCH];
    #pragma unroll
    for (int b = 0; b < BATCH; ++b) {
        v[b] = __builtin_nontemporal_load(xv + base + (size_t)b * stride);
    }

    // Phase 2: fma + streaming store.
    #pragma unroll
    for (int b = 0; b < BATCH; ++b) {
        f4 r;
        r.x = fmaf(v[b].x, s, pe.x);
        r.y = fmaf(v[b].y, s, pe.y);
        r.z = fmaf(v[b].z, s, pe.z);
        r.w = fmaf(v[b].w, s, pe.w);
        __builtin_nontemporal_store(r, ov + base + (size_t)b * stride);
    }
}

extern "C" void kernel_launch(void* const* d_in, const int* in_sizes, int n_in,
                              void* d_out, int out_size, void* d_ws, size_t ws_size,
                              hipStream_t stream) {
    const float* x = (const float*)d_in[0];
    float* out     = (float*)d_out;
    dim3 grid(TIMESTEP);
    dim3 block(256);
    Pos_embedding_39161511805397_kernel<<<grid, block, 0, stream>>>(x, out);
}

// Round 2
// 408.806 us; speedup vs baseline: 1.0946x; 1.0760x over previous
//
#include <hip/hip_runtime.h>
#include <math.h>

// Problem constants (match reference)
#define DIM_EMB 1024
#define TIMESTEP 4096
#define BATCH 16

// out[b,t,c] = x[b,t,c] * sqrt(D) + pe[t,c]
// pe[t,c] = sin(t * 10000^(-2c/D)) for even c, cos(t * 10000^(-2c/D)) for odd c.
//
// v3 (this round): FLAT LINEAR streaming. The previous structure amortized
// PE across the 16 batch planes, which forced every wave to hold 16
// outstanding loads at exactly 16 MiB (2^24) stride — power-of-two DRAM
// bank/row aliasing kept it at ~5.0 TB/s vs the 6.3-6.4 TB/s the linear
// poison fills achieve on the same runs. Here each thread owns ONE float4
// at its flat index: consecutive blocks touch consecutive 4 KiB chunks,
// identical to the float4-copy pattern that measures 6.29 TB/s.
//
// PE is recomputed per batch plane (16x redundant) but with hardware
// transcendentals it's ~8 TRANS + ~20 VALU ops/thread (~7 us chip-wide),
// issued AFTER the load so it hides entirely under HBM latency.
// v_sin_f32 / v_cos_f32 take REVOLUTIONS (cdna4_isa.md) — explicit
// reduction r = a/2pi - rint(a/2pi) in [-0.5, 0.5]. Reduction error at
// pos<=4095 is ~2.4e-4 rad — far below tolerance.

typedef float f4 __attribute__((ext_vector_type(4)));

__device__ __forceinline__ float fast_sin(float a) {
    const float INV2PI = 0.15915494309189535f;
    float r = a * INV2PI;
    r = r - rintf(r);                      // [-0.5, 0.5] revolutions
    return __builtin_amdgcn_sinf(r);       // v_sin_f32
}

__device__ __forceinline__ float fast_cos(float a) {
    const float INV2PI = 0.15915494309189535f;
    float r = a * INV2PI;
    r = r - rintf(r);
    return __builtin_amdgcn_cosf(r);       // v_cos_f32
}

__global__ __launch_bounds__(256)
void Pos_embedding_39161511805397_kernel(const float* __restrict__ x,
                                         float* __restrict__ out) {
    // Flat float4 index over the whole [B, T, D] tensor.
    const int g = blockIdx.x * 256 + threadIdx.x;     // 0 .. 16M-1
    const int c4 = g & (DIM_EMB / 4 - 1);             // float4 slot in row
    const int t  = (g >> 8) & (TIMESTEP - 1);         // time step
    const int c0 = c4 << 2;                           // first column (even)

    const f4* __restrict__ xv = (const f4*)x;
    f4* __restrict__ ov       = (f4*)out;

    // Issue the load FIRST — trig below hides under its latency.
    f4 v = __builtin_nontemporal_load(xv + g);

    const float pos = (float)t;
    // 10000^(-c/512) = exp2(k*c), k = -log2(10000)/512
    const float k  = -13.287712379549449f / 512.0f;
    const float e0 = k * (float)c0;
    const float a0 = pos * exp2f(e0);
    const float a1 = pos * exp2f(e0 + k);
    const float a2 = pos * exp2f(e0 + 2.0f * k);
    const float a3 = pos * exp2f(e0 + 3.0f * k);

    f4 pe;
    pe.x = fast_sin(a0);   // even col
    pe.y = fast_cos(a1);   // odd col
    pe.z = fast_sin(a2);   // even col
    pe.w = fast_cos(a3);   // odd col

    const float s = 32.0f;  // sqrt(1024), exact
    f4 r;
    r.x = fmaf(v.x, s, pe.x);
    r.y = fmaf(v.y, s, pe.y);
    r.z = fmaf(v.z, s, pe.z);
    r.w = fmaf(v.w, s, pe.w);
    __builtin_nontemporal_store(r, ov + g);
}

extern "C" void kernel_launch(void* const* d_in, const int* in_sizes, int n_in,
                              void* d_out, int out_size, void* d_ws, size_t ws_size,
                              hipStream_t stream) {
    const float* x = (const float*)d_in[0];
    float* out     = (float*)d_out;
    const int total_f4 = BATCH * TIMESTEP * (DIM_EMB / 4);   // 16,777,216
    dim3 grid(total_f4 / 256);                               // 65,536 blocks
    dim3 block(256);
    Pos_embedding_39161511805397_kernel<<<grid, block, 0, stream>>>(x, out);
}